// Round 5
// baseline (9233.163 us; speedup 1.0000x reference)
//
#include <hip/hip_runtime.h>
#include <cmath>

typedef __attribute__((ext_vector_type(8))) short short8;
typedef __attribute__((ext_vector_type(4))) float f32x4;
typedef __attribute__((ext_vector_type(4))) unsigned int u32x4;
typedef unsigned long long u64;
typedef unsigned int u32;

#define RS 2208             // safe-kernel A row stride in bf16
#define TICKS_MS 100000ull  // s_memrealtime ~100 MHz -> 1 ms
#define AG __ATOMIC_RELAXED, __HIP_MEMORY_SCOPE_AGENT
#define WG __ATOMIC_RELAXED, __HIP_MEMORY_SCOPE_WORKGROUP

__device__ __forceinline__ unsigned short f2bf(float x){
  u32 u = __float_as_uint(x);
  u32 r = u + 0x7FFFu + ((u >> 16) & 1u);   // round-to-nearest-even bf16
  return (unsigned short)(r >> 16);
}

__device__ __forceinline__ float tanh_fast(float x){
  float xc = fminf(fmaxf(x, -10.f), 10.f);
  float e = __expf(2.f * xc);
  return (e - 1.f) / (e + 1.f);
}

__device__ __forceinline__ u64 rtc(){ return __builtin_amdgcn_s_memrealtime(); }

// sc0 (SE-scope) ops: bypass L1, meet in the XCD-shared L2 (proven functional in
// r3/r4: FETCH_SIZE showed exchange was L2-local and results were correct).
__device__ __forceinline__ u32 ld4_sc0(const u32* p){
  u32 v;
  asm volatile("global_load_dword %0, %1, off sc0\n\ts_waitcnt vmcnt(0)"
               : "=v"(v) : "v"(p) : "memory");
  return v;
}
__device__ __forceinline__ u64 ld8_sc0(const u64* p){
  u64 v;
  asm volatile("global_load_dwordx2 %0, %1, off sc0\n\ts_waitcnt vmcnt(0)"
               : "=v"(v) : "v"(p) : "memory");
  return v;
}
__device__ __forceinline__ void st8_sc0(u64* p, u64 v){
  asm volatile("global_store_dwordx2 %0, %1, off sc0" :: "v"(p), "v"(v) : "memory");
}
__device__ __forceinline__ u32x4 ld16_sc0(const u64* p){
  u32x4 v;
  asm volatile("global_load_dwordx4 %0, %1, off sc0\n\ts_waitcnt vmcnt(0)"
               : "=v"(v) : "v"(p) : "memory");
  return v;
}

// Pre-swizzle [w_res ; w_in] (K=2176 x 2048 cols) into bf16 MFMA B-fragment order.
// short8 index = ((gcg*68 + fu)*64 + l); k = fu*32 + (l>>4)*8 + j, col = gcg*16 + (l&15).
__global__ void bswz_kernel(const float* __restrict__ wres,
                            const float* __restrict__ win,
                            unsigned short* __restrict__ B){
  int tid = blockIdx.x * 256 + threadIdx.x;
  int l   = tid & 63;
  int cf  = tid >> 6;
  int f   = cf % 34;
  int gk  = cf / 34;
  int ks  = gk & 1;
  int gcg = gk >> 1;
  int col = (gcg << 4) + (l & 15);
  int k0  = ks * 1088 + (f << 5) + ((l >> 4) << 3);
  short8 vv;
  #pragma unroll
  for (int j = 0; j < 8; ++j){
    int k = k0 + j;
    float v = (k < 2048) ? wres[(size_t)k * 2048 + col]
                         : win[(size_t)(k - 2048) * 2048 + col];
    vv[j] = (short)f2bf(v);
  }
  *((short8*)(B + (size_t)tid * 8)) = vv;
}

// out[b][t][0:128] = inputs  (concat head).
__global__ void copy_in_kernel(const float* __restrict__ in, float* __restrict__ out){
  int i = blockIdx.x * 256 + threadIdx.x;
  int bt = i >> 5;
  int d4 = i & 31;
  float4 v = ((const float4*)in)[i];
  ((float4*)(out + (size_t)bt * 2176))[d4] = v;
}

// ex[2][8][512] u64 data (parity1 tag-init kept for the safe kernel's protocol);
// ctrl u32[16] at ex[8192]; tslots[256] u64 at ex[8200]; ring counters at
// ex[8456 + r*2] (16B-spaced u32). All zeroed each launch.
__global__ void exinit_kernel(u64* __restrict__ ex){
  int i = blockIdx.x * 256 + threadIdx.x;   // 35*256 = 8960 entries
  if (i < 8192)      ex[i] = (i < 4096) ? 0ULL : 0x0001000100010001ULL;
  else if (i < 8960) ex[i] = 0ULL;
}

// ---------------- WIDE: 256 blocks x 256 threads, 1 block/CU ----------------
// Self-organized co-XCD rings (HW_REG_XCC_ID + rank claim), verified by bounded
// sc0 lockstep ping-pong. NEW vs r3/r4: counter-signaled exchange -- producers
// publish data (sc0), drain stores, then one plain global_atomic_add per wave
// (atomics execute at the local XCD L2 = the ring's shared point); consumers
// spin on ONE 4B line (tid 0 only) and then read the row data in ONE sc0 pass.
// Removes the 64-line-per-block poll flood that was congesting the L2 banks.
// verdict 1: sc0/L2; 2: agent/LLC, same structure; 3: exit -> esn_safe.
__global__ void __launch_bounds__(256, 1) esn_wide(
    const float* __restrict__ inputs,
    const float* __restrict__ b_in,
    const unsigned short* __restrict__ Bsw,
    u64* __restrict__ ex,
    float* __restrict__ out)
{
  __shared__ __align__(16) unsigned short As[2][2176]; // [parity][2048 state + 128 x_t]
  __shared__ int s_r, s_cb, s_mode;

  const int tid = threadIdx.x;
  u32* ctrl   = (u32*)(ex + 8192);           // [0]=ticket [1]=ok [2]=badA [3]=badP [4]=verdict [8..15]=rank ctrs
  u64* tslots = ex + 8200;

  // ---- clock-bounded pre-flight (tid 0; leader = ticket 0, always exists) ----
  if (tid == 0){
    u32 x  = __builtin_amdgcn_s_getreg(6164);   // hwreg(HW_REG_XCC_ID=20, 0, 4)
    u32 tk = __hip_atomic_fetch_add(&ctrl[0], 1u, AG);
    u32 rank = __hip_atomic_fetch_add(&ctrl[8 + (x & 7u)], 1u, AG);
    int okA = (x < 8u) && (rank < 32u);
    s_r  = (int)(x & 7u);
    s_cb = (int)(rank & 31u);
    if (!okA){
      __hip_atomic_fetch_add(&ctrl[2], 1u, AG);             // badA
    } else {
      u64* my = &tslots[(x << 5) | rank];
      u64* pa = &tslots[(x << 5) | ((rank + 1u) & 31u)];    // ring neighbor, same XCD
      int ok = 1;
      for (u64 rd = 1; rd <= 4 && ok; ++rd){                // lockstep: needs FRESH values
        st8_sc0(my, rd);
        u64 tend = rtc() + TICKS_MS;
        u64 v;
        do { v = ld8_sc0(pa); } while (v < rd && rtc() < tend);
        ok = (v >= rd) ? 1 : 0;
      }
      __hip_atomic_fetch_add(&ctrl[ok ? 1 : 3], 1u, AG);    // ok / badP
    }
    if (tk == 0u){                                          // leader decides once
      u64 tend = rtc() + 3 * TICKS_MS;
      u32 a, bA, bP;
      do {
        a  = __hip_atomic_load(&ctrl[1], AG);
        bA = __hip_atomic_load(&ctrl[2], AG);
        bP = __hip_atomic_load(&ctrl[3], AG);
      } while (a + bA + bP < 256u && rtc() < tend);
      u32 v = (a == 256u) ? 1u : ((bA == 0u && a + bA + bP == 256u) ? 2u : 3u);
      __hip_atomic_store(&ctrl[4], v, AG);
    }
    u64 tend = rtc() + 50 * TICKS_MS;
    u32 v;
    do { v = __hip_atomic_load(&ctrl[4], AG); } while (v == 0u && rtc() < tend);
    s_mode = (v == 1u) ? 1 : ((v == 2u) ? 0 : -1);
  }
  __syncthreads();
  const int mode = s_mode;
  if (mode < 0) return;            // esn_safe takes over (verdict 3)
  const bool fast = (mode == 1);
  const int r  = s_r;
  const int cb = s_cb;             // 0..31: cols [cb*64, cb*64+64)

  const int w   = tid >> 6;        // wave 0..3 = col-group
  const int l   = tid & 63;
  const int m16 = l & 15;
  const int q   = l >> 4;
  const int gcg = (cb << 2) + w;   // 0..127
  const int colw0 = gcg << 4;

  // B fragments for full K=2176 (68 short8; lands in unified VGPR/AGPR file)
  short8 Bf[68];
  {
    const short8* bp = (const short8*)Bsw + (size_t)gcg * (68 * 64) + l;
    #pragma unroll
    for (int f = 0; f < 68; ++f) Bf[f] = bp[f * 64];
  }
  const float bias = b_in[colw0 + m16];
  float s = 0.f;
  const float* xr = inputs + (size_t)r * 1024 * 128;
  u32* ctr = (u32*)(ex + 8456 + ((size_t)r << 1));   // ring counter, 16B-spaced

  float4 xv;
  if (tid < 32) xv = ((const float4*)xr)[tid];      // prefetch x_0

  for (int t = 0; t < 1024; ++t){
    const int p = t & 1;
    unsigned short* Ap = &As[p][0];

    // stage x_t from regs; issue prefetch of x_{t+1} (overlaps the wait)
    if (tid < 32){
      u64 pk = (u64)f2bf(xv.x) | ((u64)f2bf(xv.y) << 16)
             | ((u64)f2bf(xv.z) << 32) | ((u64)f2bf(xv.w) << 48);
      *((u64*)&Ap[2048 + (tid << 2)]) = pk;
      if (t < 1023) xv = ((const float4*)(xr + (size_t)(t + 1) * 128))[tid];
    }
    // wait for ring counter: s_t fully published <=> ctr >= 128*t (32 blk x 4 waves)
    if (tid == 0){
      const u32 need = (u32)t * 128u;
      if (need){
        u32 c = fast ? ld4_sc0(ctr) : __hip_atomic_load(ctr, AG);
        if (c < need){
          u64 tend = rtc() + TICKS_MS;       // liveness guard: never hang
          do { c = fast ? ld4_sc0(ctr) : __hip_atomic_load(ctr, AG); }
          while (c < need && rtc() < tend);
        }
      }
    }
    __syncthreads();

    // ONE data pass: 16B/thread of the 4KB row (no tags, no re-poll)
    {
      const u64* srcb = ex + ((size_t)p * 8 + r) * 512;
      u64 v01, v23;
      if (fast){
        u32x4 v = ld16_sc0(srcb + (tid << 1));
        v01 = (u64)v.x | ((u64)v.y << 32);
        v23 = (u64)v.z | ((u64)v.w << 32);
      } else {
        v01 = __hip_atomic_load(&srcb[(tid << 1)],     AG);
        v23 = __hip_atomic_load(&srcb[(tid << 1) + 1], AG);
      }
      *((u64*)&Ap[(tid << 3)])     = v01;
      *((u64*)&Ap[(tid << 3) + 4]) = v23;
    }
    __syncthreads();

    // MFMA: full K=2176, 68 x 16x16x32, 4 interleaved acc chains, M=1 broadcast
    f32x4 a0 = {0,0,0,0}, a1 = {0,0,0,0}, a2 = {0,0,0,0}, a3 = {0,0,0,0};
    {
      const unsigned short* Ab = Ap + (q << 3);
      #pragma unroll
      for (int f = 0; f < 68; f += 4){
        short8 x0 = *((const short8*)(Ab + ((f + 0) << 5)));
        short8 x1 = *((const short8*)(Ab + ((f + 1) << 5)));
        short8 x2 = *((const short8*)(Ab + ((f + 2) << 5)));
        short8 x3 = *((const short8*)(Ab + ((f + 3) << 5)));
        a0 = __builtin_amdgcn_mfma_f32_16x16x32_bf16(x0, Bf[f + 0], a0, 0, 0, 0);
        a1 = __builtin_amdgcn_mfma_f32_16x16x32_bf16(x1, Bf[f + 1], a1, 0, 0, 0);
        a2 = __builtin_amdgcn_mfma_f32_16x16x32_bf16(x2, Bf[f + 2], a2, 0, 0, 0);
        a3 = __builtin_amdgcn_mfma_f32_16x16x32_bf16(x3, Bf[f + 3], a3, 0, 0, 0);
      }
    }
    float nv = 0.f;
    if (l < 16){
      float pre = ((a0[0] + a1[0]) + (a2[0] + a3[0])) + bias;
      nv = 0.5f * s + 0.5f * tanh_fast(pre);
      s = nv;
      // publish raw bf16 (no tag bit needed with counter signaling)
      u32 b0 = (u32)f2bf(nv);
      u32 pr = b0 | (((u32)__shfl_xor((int)b0, 1)) << 16);
      u64 e  = (u64)pr | ((u64)(u32)__shfl_xor((int)pr, 2) << 32);
      if ((m16 & 3) == 0){
        u64* exw = ex + ((size_t)((t + 1) & 1) * 8 + r) * 512;
        u64* dst = &exw[(colw0 + m16) >> 2];
        if (fast) st8_sc0(dst, e);
        else __hip_atomic_store(dst, e, AG);
      }
    }
    // drain this wave's publish stores, then ONE counter bump per wave
    asm volatile("s_waitcnt vmcnt(0)" ::: "memory");
    if (l == 0){
      if (fast) __hip_atomic_fetch_add(ctr, 1u, WG);   // plain atomic -> local XCD L2
      else      __hip_atomic_fetch_add(ctr, 1u, AG);
    }
    if (l < 16){
      const int u = colw0 + m16;
      float pw = (u & 1) ? nv : nv * nv;               // PowerIndex: even u squared
      out[((size_t)r * 1024 + t) * 2176 + 128 + u] = pw;
    }
  }
}

// ---------------- SAFE: verbatim proven 3.08ms kernel, verdict-gated ----------------
__global__ void __launch_bounds__(512, 2) esn_safe(
    const float* __restrict__ inputs,
    const float* __restrict__ b_in,
    const unsigned short* __restrict__ Bsw,
    u64* __restrict__ ex,
    float* __restrict__ out)
{
  __shared__ __align__(16) unsigned short As[2 * RS];
  __shared__ float red[2][4][16][2];
  __shared__ int g;

  if (threadIdx.x == 0)
    g = (int)__hip_atomic_load(&((u32*)(ex + 8192))[4], AG);
  __syncthreads();
  if (g == 1 || g == 2) return;    // wide kernel already produced the output

  const int tid = threadIdx.x;
  const int blk = blockIdx.x;      // 0..127
  const int r0  = (blk >> 5) << 1;
  const int cb  = blk & 31;
  const int wv  = tid >> 6;
  const int l   = tid & 63;
  const int m16 = l & 15;
  const int q   = l >> 4;
  const int cg  = wv >> 1;
  const int ks  = wv & 1;
  const int gcg = (cb << 2) + cg;
  const int colw0 = gcg << 4;

  short8 Bf[34];
  {
    const short8* bp = (const short8*)Bsw + (size_t)((gcg << 1) + ks) * 34 * 64 + l;
    #pragma unroll
    for (int f = 0; f < 34; ++f) Bf[f] = bp[f * 64];
  }
  const float bias = b_in[colw0 + m16];
  float s0 = 0.f, s1 = 0.f;

  const float* xr0 = inputs + (size_t)r0 * 1024 * 128;
  const u64 M = 0x0001000100010001ULL;

  for (int t = 0; t < 1024; ++t){
    if (tid < 64){
      const int row = tid >> 5;
      const int c   = tid & 31;
      float4 xv = ((const float4*)(xr0 + ((size_t)row * 1024 + t) * 128))[c];
      u64 pk = (u64)f2bf(xv.x) | ((u64)f2bf(xv.y) << 16)
             | ((u64)f2bf(xv.z) << 32) | ((u64)f2bf(xv.w) << 48);
      *((u64*)&As[row * RS + 2048 + (c << 2)]) = pk;
    }
    {
      u64* srcb = ex + ((size_t)(t & 1) * 8 + r0) * 512;
      const u64 wantm = ((t >> 1) & 1) ? M : 0ULL;
      u64 v0 = __hip_atomic_load(&srcb[tid],       AG);
      u64 v1 = __hip_atomic_load(&srcb[512 + tid], AG);
      u32 pend = 3;
      while (pend){
        u32 np = 0;
        if (pend & 1){
          if ((v0 & M) == wantm) *((u64*)&As[tid << 2]) = v0;
          else np |= 1;
        }
        if (pend & 2){
          if ((v1 & M) == wantm) *((u64*)&As[RS + (tid << 2)]) = v1;
          else np |= 2;
        }
        pend = np;
        if (pend & 1) v0 = __hip_atomic_load(&srcb[tid],       AG);
        if (pend & 2) v1 = __hip_atomic_load(&srcb[512 + tid], AG);
      }
    }
    __syncthreads();

    f32x4 acc0 = {0.f,0.f,0.f,0.f}, acc1 = {0.f,0.f,0.f,0.f};
    {
      const unsigned short* Ab = &As[(m16 & 1) * RS + ks * 1088 + (q << 3)];
      #pragma unroll
      for (int f = 0; f < 34; f += 2){
        short8 a0 = *((const short8*)(Ab + (f << 5)));
        short8 a1 = *((const short8*)(Ab + ((f + 1) << 5)));
        acc0 = __builtin_amdgcn_mfma_f32_16x16x32_bf16(a0, Bf[f],     acc0, 0, 0, 0);
        acc1 = __builtin_amdgcn_mfma_f32_16x16x32_bf16(a1, Bf[f + 1], acc1, 0, 0, 0);
      }
    }
    float p0 = acc0[0] + acc1[0];
    float p1 = acc0[1] + acc1[1];
    if (ks == 1 && l < 16){
      red[t & 1][cg][m16][0] = p0;
      red[t & 1][cg][m16][1] = p1;
    }
    __syncthreads();

    if (ks == 0 && l < 16){
      p0 += red[t & 1][cg][m16][0];
      p1 += red[t & 1][cg][m16][1];
      float nv0 = 0.5f * s0 + 0.5f * tanh_fast(p0 + bias);
      float nv1 = 0.5f * s1 + 0.5f * tanh_fast(p1 + bias);
      s0 = nv0; s1 = nv1;
      const u32 bit = (u32)(((t + 1) >> 1) & 1);
      u32 b0 = ((u32)f2bf(nv0) & 0xFFFEu) | bit;
      u32 b1 = ((u32)f2bf(nv1) & 0xFFFEu) | bit;
      u32 pr0 = b0 | (((u32)__shfl_xor((int)b0, 1)) << 16);
      u32 pr1 = b1 | (((u32)__shfl_xor((int)b1, 1)) << 16);
      u64 e0 = (u64)pr0 | ((u64)(u32)__shfl_xor((int)pr0, 2) << 32);
      u64 e1 = (u64)pr1 | ((u64)(u32)__shfl_xor((int)pr1, 2) << 32);
      const int u = colw0 + m16;
      if ((m16 & 3) == 0){
        u64* exw = ex + ((size_t)((t + 1) & 1) * 8 + r0) * 512;
        const int p = (colw0 + m16) >> 2;
        __hip_atomic_store(&exw[p],       e0, AG);
        __hip_atomic_store(&exw[512 + p], e1, AG);
      }
      float pw0 = (u & 1) ? nv0 : nv0 * nv0;
      float pw1 = (u & 1) ? nv1 : nv1 * nv1;
      out[((size_t)r0 * 1024 + t) * 2176 + 128 + u] = pw0;
      out[((size_t)(r0 + 1) * 1024 + t) * 2176 + 128 + u] = pw1;
    }
  }
}

extern "C" void kernel_launch(void* const* d_in, const int* in_sizes, int n_in,
                              void* d_out, int out_size, void* d_ws, size_t ws_size,
                              hipStream_t stream){
  const float* inputs = (const float*)d_in[0];   // [8,1024,128]
  const float* w_in   = (const float*)d_in[1];   // [128,2048]
  const float* b_in   = (const float*)d_in[2];   // [2048]
  const float* w_res  = (const float*)d_in[3];   // [2048,2048]
  float* out = (float*)d_out;

  u64* ex = (u64*)d_ws;                                         // 8960 u64 = 71680 B
  unsigned short* Bsw = (unsigned short*)((char*)d_ws + 71680); // 8,912,896 B swizzled weights

  exinit_kernel<<<35, 256, 0, stream>>>(ex);
  bswz_kernel<<<2176, 256, 0, stream>>>(w_res, w_in, Bsw);
  copy_in_kernel<<<1024, 256, 0, stream>>>(inputs, out);
  esn_wide<<<256, 256, 0, stream>>>(inputs, b_in, Bsw, ex, out);
  esn_safe<<<128, 512, 0, stream>>>(inputs, b_in, Bsw, ex, out);
}

// Round 6
// 3398.018 us; speedup vs baseline: 2.7172x; 2.7172x over previous
//
#include <hip/hip_runtime.h>
#include <cmath>

typedef __attribute__((ext_vector_type(8))) short short8;
typedef __attribute__((ext_vector_type(4))) float f32x4;
typedef unsigned long long u64;
typedef unsigned int u32;

#define RS 2208   // A row stride in bf16 (2176 data + 32 pad -> rows offset by 16 banks)
#define AG __ATOMIC_RELAXED, __HIP_MEMORY_SCOPE_AGENT

__device__ __forceinline__ unsigned short f2bf(float x){
  u32 u = __float_as_uint(x);
  u32 r = u + 0x7FFFu + ((u >> 16) & 1u);   // round-to-nearest-even bf16
  return (unsigned short)(r >> 16);
}

__device__ __forceinline__ float tanh_fast(float x){
  float xc = fminf(fmaxf(x, -10.f), 10.f);   // tanh(10)=1-4e-9; also keeps exp finite
  float e = __expf(2.f * xc);
  return (e - 1.f) / (e + 1.f);
}

// Pre-swizzle [w_res ; w_in] (K=2176 x 2048 cols) into bf16 MFMA B-fragment order.
// short8 index = ((gcg*68 + fu)*64 + l); k = fu*32 + (l>>4)*8 + j, col = gcg*16 + (l&15).
// 4-way K-split waves use fu ranges [ks*17, ks*17+17) -- same bytes, no change.
__global__ void bswz_kernel(const float* __restrict__ wres,
                            const float* __restrict__ win,
                            unsigned short* __restrict__ B){
  int tid = blockIdx.x * 256 + threadIdx.x;
  int l   = tid & 63;
  int cf  = tid >> 6;          // (gcg*2+ks2)*34 + f
  int f   = cf % 34;
  int gk  = cf / 34;
  int ks  = gk & 1;
  int gcg = gk >> 1;
  int col = (gcg << 4) + (l & 15);
  int k0  = ks * 1088 + (f << 5) + ((l >> 4) << 3);
  short8 vv;
  #pragma unroll
  for (int j = 0; j < 8; ++j){
    int k = k0 + j;
    float v = (k < 2048) ? wres[(size_t)k * 2048 + col]
                         : win[(size_t)(k - 2048) * 2048 + col];
    vv[j] = (short)f2bf(v);
  }
  *((short8*)(B + (size_t)tid * 8)) = vv;
}

// out[b][t][0:128] = inputs  (concat head).  262144 float4s = 1024 blocks x 256.
__global__ void copy_in_kernel(const float* __restrict__ in, float* __restrict__ out){
  int i = blockIdx.x * 256 + threadIdx.x;
  int bt = i >> 5;
  int d4 = i & 31;
  float4 v = ((const float4*)in)[i];
  ((float4*)(out + (size_t)bt * 2176))[d4] = v;
}

// Exchange init: ex[2][8][512] u64.  Parity 0 = 0 (tag-bit 0, s_0 = 0 -> valid for t=0).
// Parity 1 = all-bf16-LSB=1 (tag-bit 1): t=1 wants bit 0 -> init rejected until real data.
__global__ void exinit_kernel(u64* __restrict__ ex){
  int i = blockIdx.x * 256 + threadIdx.x;   // 8192 entries
  ex[i] = (i < 4096) ? 0ULL : 0x0001000100010001ULL;
}

// Persistent ESN scan: 128 blocks x 1024 threads (16 waves/CU on the active CUs).
// Block: 2 batch rows {r0, r0+1} x 64 cols.  Waves: 4 col-groups x 4 K-quarters
// (K=544, 17 fragments/wave -> ~115 VGPR, 4 waves/SIMD) + LDS 4-way reduce.
// Exchange: PROVEN baseline protocol -- agent-scope (LLC) tagged u64 entries,
// tag bit = ((t>>1)&1) in every bf16 LSB, parity-double-buffered.  One entry per
// thread (1024 threads <-> 2 rows x 512 entries).
__global__ void __launch_bounds__(1024) esn_persist(
    const float* __restrict__ inputs,
    const float* __restrict__ b_in,
    const unsigned short* __restrict__ Bsw,
    u64* __restrict__ ex,          // ex[parity 2][row 8][512 entries]
    float* __restrict__ out)
{
  __shared__ __align__(16) unsigned short As[2 * RS];  // [row 0/1][2048 state + 128 x_t + pad]
  __shared__ float red[2][3][4][16][2];                // [parity][ks-1][cg][m16][row]

  const int tid = threadIdx.x;
  const int blk = blockIdx.x;      // 0..127
  const int r0  = (blk >> 5) << 1; // batch rows {r0, r0+1}
  const int cb  = blk & 31;        // column block: cols [cb*64, cb*64+64)
  const int wv  = tid >> 6;        // 0..15
  const int l   = tid & 63;
  const int m16 = l & 15;
  const int q   = l >> 4;
  const int cg  = wv >> 2;         // col-group 0..3 (16 cols each)
  const int ks  = wv & 3;          // K-quarter 0..3 (K=544 each)
  const int gcg = (cb << 2) + cg;  // global col-group 0..127
  const int colw0 = gcg << 4;

  // B fragments in registers for the whole scan (17 per wave = 68 VGPRs)
  short8 Bf[17];
  {
    const short8* bp = (const short8*)Bsw + (size_t)(gcg * 68 + ks * 17) * 64 + l;
    #pragma unroll
    for (int f = 0; f < 17; ++f) Bf[f] = bp[f * 64];
  }
  const float bias = b_in[colw0 + m16];
  float s0 = 0.f, s1 = 0.f;        // fp32 leak-path state (ks==0, lanes<16)

  const float* xr0 = inputs + (size_t)r0 * 1024 * 128;
  const u64 M = 0x0001000100010001ULL;

  float4 xv;
  if (tid < 64) xv = ((const float4*)(xr0 + (size_t)(tid >> 5) * 1024 * 128))[tid & 31];

  for (int t = 0; t < 1024; ++t){
    // ---- stage x_t from regs (64 threads, packed 8B, bank-clean); prefetch x_{t+1} ----
    if (tid < 64){
      const int row = tid >> 5;
      const int c   = tid & 31;
      u64 pk = (u64)f2bf(xv.x) | ((u64)f2bf(xv.y) << 16)
             | ((u64)f2bf(xv.z) << 32) | ((u64)f2bf(xv.w) << 48);
      *((u64*)&As[row * RS + 2048 + (c << 2)]) = pk;
      if (t < 1023)
        xv = ((const float4*)(xr0 + ((size_t)row * 1024 + t + 1) * 128))[c];
    }
    // ---- poll ONE tagged entry/thread (rows r0,r0+1 are consecutive in ex) ----
    {
      u64* srcb = ex + ((size_t)(t & 1) * 8 + r0) * 512;
      const u64 want = ((t >> 1) & 1) ? M : 0ULL;
      u64 v = __hip_atomic_load(&srcb[tid], AG);
      while ((v & M) != want) v = __hip_atomic_load(&srcb[tid], AG);
      *((u64*)&As[(tid >> 9) * RS + ((tid & 511) << 2)]) = v;
    }
    __syncthreads();

    // ---- MFMA: M=2, K=544 per wave, 17 x 16x16x32, 2 interleaved acc chains.
    // Unconditional A read, row = m16&1 (8 lanes/address LDS broadcast);
    // D rows: even m = batch row0, odd m = row1; lanes 0..15 regs 0,1 are consumed.
    f32x4 acc0 = {0.f,0.f,0.f,0.f}, acc1 = {0.f,0.f,0.f,0.f};
    {
      const unsigned short* Ab = &As[(m16 & 1) * RS + ks * 544 + (q << 3)];
      #pragma unroll
      for (int f = 0; f < 16; f += 2){
        short8 a0 = *((const short8*)(Ab + (f << 5)));
        short8 a1 = *((const short8*)(Ab + ((f + 1) << 5)));
        acc0 = __builtin_amdgcn_mfma_f32_16x16x32_bf16(a0, Bf[f],     acc0, 0, 0, 0);
        acc1 = __builtin_amdgcn_mfma_f32_16x16x32_bf16(a1, Bf[f + 1], acc1, 0, 0, 0);
      }
      short8 a2 = *((const short8*)(Ab + (16 << 5)));
      acc0 = __builtin_amdgcn_mfma_f32_16x16x32_bf16(a2, Bf[16], acc0, 0, 0, 0);
    }
    // C/D: col=l&15, row=q*4+reg -> batch rows 0,1 live in lanes 0..15, regs 0,1
    float p0 = acc0[0] + acc1[0];
    float p1 = acc0[1] + acc1[1];
    if (ks != 0 && l < 16){
      red[t & 1][ks - 1][cg][m16][0] = p0;
      red[t & 1][ks - 1][cg][m16][1] = p1;
    }
    __syncthreads();

    // ---- ks==0 lanes<16: reduce, tanh, leak, publish FIRST, then out stores ----
    if (ks == 0 && l < 16){
      p0 += red[t & 1][0][cg][m16][0] + red[t & 1][1][cg][m16][0] + red[t & 1][2][cg][m16][0];
      p1 += red[t & 1][0][cg][m16][1] + red[t & 1][1][cg][m16][1] + red[t & 1][2][cg][m16][1];
      float nv0 = 0.5f * s0 + 0.5f * tanh_fast(p0 + bias);
      float nv1 = 0.5f * s1 + 0.5f * tanh_fast(p1 + bias);
      s0 = nv0; s1 = nv1;
      const u32 bit = (u32)(((t + 1) >> 1) & 1);
      u32 b0 = ((u32)f2bf(nv0) & 0xFFFEu) | bit;   // tag-bit in bf16 LSB
      u32 b1 = ((u32)f2bf(nv1) & 0xFFFEu) | bit;
      // pack 4 lanes' cols into one u64 (valid on lanes m16%4==0)
      u32 pr0 = b0 | (((u32)__shfl_xor((int)b0, 1)) << 16);
      u32 pr1 = b1 | (((u32)__shfl_xor((int)b1, 1)) << 16);
      u64 e0 = (u64)pr0 | ((u64)(u32)__shfl_xor((int)pr0, 2) << 32);
      u64 e1 = (u64)pr1 | ((u64)(u32)__shfl_xor((int)pr1, 2) << 32);
      const int u = colw0 + m16;
      if ((m16 & 3) == 0){
        u64* exw = ex + ((size_t)((t + 1) & 1) * 8 + r0) * 512;
        const int p = (colw0 + m16) >> 2;
        __hip_atomic_store(&exw[p],       e0, AG);
        __hip_atomic_store(&exw[512 + p], e1, AG);
      }
      float pw0 = (u & 1) ? nv0 : nv0 * nv0;       // PowerIndex: even u squared
      float pw1 = (u & 1) ? nv1 : nv1 * nv1;
      out[((size_t)r0 * 1024 + t) * 2176 + 128 + u] = pw0;
      out[((size_t)(r0 + 1) * 1024 + t) * 2176 + 128 + u] = pw1;
    }
    // no third barrier: As/x writes for t+1 happen after barrier 2; red is
    // parity-double-buffered; As reads of step t completed before barrier 2.
  }
}

extern "C" void kernel_launch(void* const* d_in, const int* in_sizes, int n_in,
                              void* d_out, int out_size, void* d_ws, size_t ws_size,
                              hipStream_t stream){
  const float* inputs = (const float*)d_in[0];   // [8,1024,128]
  const float* w_in   = (const float*)d_in[1];   // [128,2048]
  const float* b_in   = (const float*)d_in[2];   // [2048]
  const float* w_res  = (const float*)d_in[3];   // [2048,2048]
  float* out = (float*)d_out;

  u64* ex = (u64*)d_ws;                                         // 2*8*512*8 = 65536 B
  unsigned short* Bsw = (unsigned short*)((char*)d_ws + 65536); // 8,912,896 B swizzled weights

  exinit_kernel<<<32, 256, 0, stream>>>(ex);
  bswz_kernel<<<2176, 256, 0, stream>>>(w_res, w_in, Bsw);
  copy_in_kernel<<<1024, 256, 0, stream>>>(inputs, out);
  esn_persist<<<128, 1024, 0, stream>>>(inputs, b_in, Bsw, ex, out);
}

// Round 7
// 3116.706 us; speedup vs baseline: 2.9625x; 1.0903x over previous
//
#include <hip/hip_runtime.h>
#include <cmath>

typedef __attribute__((ext_vector_type(8))) short short8;
typedef __attribute__((ext_vector_type(4))) float f32x4;
typedef __attribute__((ext_vector_type(4))) unsigned int u32x4;
typedef unsigned long long u64;
typedef unsigned int u32;

#define RS 2208   // A row stride in bf16 (2176 data + 32 pad -> rows offset by 16 banks)
#define AG __ATOMIC_RELAXED, __HIP_MEMORY_SCOPE_AGENT

__device__ __forceinline__ unsigned short f2bf(float x){
  u32 u = __float_as_uint(x);
  u32 r = u + 0x7FFFu + ((u >> 16) & 1u);   // round-to-nearest-even bf16
  return (unsigned short)(r >> 16);
}

__device__ __forceinline__ float tanh_fast(float x){
  float xc = fminf(fmaxf(x, -10.f), 10.f);   // tanh(10)=1-4e-9; also keeps exp finite
  float e = __expf(2.f * xc);
  return (e - 1.f) / (e + 1.f);
}

// Pre-swizzle [w_res ; w_in] (K=2176 x 2048 cols) into bf16 MFMA B-fragment order.
// Layout: [gcg 0..127][ks 0..1][f 0..33][lane 0..63][j 0..7]:
//   k = ks*1088 + f*32 + (l>>4)*8 + j, col = gcg*16 + (l&15).
__global__ void bswz_kernel(const float* __restrict__ wres,
                            const float* __restrict__ win,
                            unsigned short* __restrict__ B){
  int tid = blockIdx.x * 256 + threadIdx.x;
  int l   = tid & 63;
  int cf  = tid >> 6;          // (gcg*2+ks)*34 + f
  int f   = cf % 34;
  int gk  = cf / 34;
  int ks  = gk & 1;
  int gcg = gk >> 1;
  int col = (gcg << 4) + (l & 15);
  int k0  = ks * 1088 + (f << 5) + ((l >> 4) << 3);
  short8 vv;
  #pragma unroll
  for (int j = 0; j < 8; ++j){
    int k = k0 + j;
    float v = (k < 2048) ? wres[(size_t)k * 2048 + col]
                         : win[(size_t)(k - 2048) * 2048 + col];
    vv[j] = (short)f2bf(v);
  }
  *((short8*)(B + (size_t)tid * 8)) = vv;
}

// out[b][t][0:128] = inputs  (concat head).  262144 float4s = 1024 blocks x 256.
__global__ void copy_in_kernel(const float* __restrict__ in, float* __restrict__ out){
  int i = blockIdx.x * 256 + threadIdx.x;
  int bt = i >> 5;
  int d4 = i & 31;
  float4 v = ((const float4*)in)[i];
  ((float4*)(out + (size_t)bt * 2176))[d4] = v;
}

// Exchange init: ex[2][8][512] u64.  Parity 0 = 0 (tag-bit 0, s_0 = 0 -> valid for t=0).
// Parity 1 = all-bf16-LSB=1 (tag-bit 1): t=1 wants bit 0 -> init rejected until real data.
__global__ void exinit_kernel(u64* __restrict__ ex){
  int i = blockIdx.x * 256 + threadIdx.x;   // 8192 entries
  ex[i] = (i < 4096) ? 0ULL : 0x0001000100010001ULL;
}

// Persistent ESN scan: 128 blocks x 512 threads = 4 row-pairs x 32 col-blocks of 64 cols.
// Exchange entries: u64 = 4 consecutive columns' bf16 with LSB = step tag-bit ((t>>1)&1).
// Double-buffered by parity; stale slot is always step t-2 whose tag-bit differs.
// r7 transport fix: (a) publish via atomic RMW (swap) so the line is pulled into and
// stays resident at the MALL/LLC coherence point (plain agent stores appeared to leave
// the lines DRAM-only: ~240 KB/step HBM FETCH from a 64 KB hot region); (b) polls are
// one 16B sc0+sc1 load per thread (pair-adjacent entries, halves request count), with a
// periodic proven __hip_atomic_load fallback so liveness never depends on the new path.
__global__ void __launch_bounds__(512, 2) esn_persist(
    const float* __restrict__ inputs,
    const float* __restrict__ b_in,
    const unsigned short* __restrict__ Bsw,
    u64* __restrict__ ex,          // ex[parity 2][row 8][512 entries]
    float* __restrict__ out)
{
  __shared__ __align__(16) unsigned short As[2 * RS];  // [row 0/1][k: 2048 state + 128 x_t + pad]
  __shared__ float red[2][4][16][2];                   // [parity][cg][m16][row]

  const int tid = threadIdx.x;
  const int blk = blockIdx.x;      // 0..127
  const int r0  = (blk >> 5) << 1; // batch rows {r0, r0+1}
  const int cb  = blk & 31;        // column block: cols [cb*64, cb*64+64)
  const int wv  = tid >> 6;        // 0..7
  const int l   = tid & 63;
  const int m16 = l & 15;
  const int q   = l >> 4;
  const int cg  = wv >> 1;         // col-group 0..3 (16 cols each)
  const int ks  = wv & 1;          // K-split 0/1 (K=1088 each)
  const int gcg = (cb << 2) + cg;  // global col-group 0..127
  const int colw0 = gcg << 4;

  // B fragments in registers for the whole scan (34 per wave = 136 VGPRs)
  short8 Bf[34];
  {
    const short8* bp = (const short8*)Bsw + (size_t)((gcg << 1) + ks) * 34 * 64 + l;
    #pragma unroll
    for (int f = 0; f < 34; ++f) Bf[f] = bp[f * 64];
  }
  const float bias = b_in[colw0 + m16];
  float s0 = 0.f, s1 = 0.f;        // fp32 leak-path state (ks==0, lanes<16)

  const float* xr0 = inputs + (size_t)r0 * 1024 * 128;
  const u64 M = 0x0001000100010001ULL;

  // register x-prefetch (r6-proven): overlaps the global x load with the poll
  float4 xv;
  if (tid < 64) xv = ((const float4*)(xr0 + (size_t)(tid >> 5) * 1024 * 128))[tid & 31];

  for (int t = 0; t < 1024; ++t){
    // ---- stage x_t from regs: 64 threads, packed 8B LDS writes; prefetch x_{t+1} ----
    if (tid < 64){
      const int row = tid >> 5;
      const int c   = tid & 31;
      u64 pk = (u64)f2bf(xv.x) | ((u64)f2bf(xv.y) << 16)
             | ((u64)f2bf(xv.z) << 32) | ((u64)f2bf(xv.w) << 48);
      *((u64*)&As[row * RS + 2048 + (c << 2)]) = pk;
      if (t < 1023)
        xv = ((const float4*)(xr0 + ((size_t)row * 1024 + t + 1) * 128))[c];
    }
    // ---- poll: one 16B load/thread covering its 2 adjacent entries ----
    // rows r0, r0+1 are contiguous in ex => entries [0,1024) span both rows.
    {
      u64* srcb = ex + ((size_t)(t & 1) * 8 + r0) * 512;   // 1024 u64 across 2 rows
      const u64 want = ((t >> 1) & 1) ? M : 0ULL;
      const u64* myp = &srcb[tid << 1];
      u64 v0, v1;
      u32 it = 0;
      for (;;){
        if ((it & 7u) == 7u){           // proven-path fallback: liveness guaranteed
          v0 = __hip_atomic_load(&myp[0], AG);
          v1 = __hip_atomic_load(&myp[1], AG);
        } else {
          u32x4 v;
          asm volatile("global_load_dwordx4 %0, %1, off sc0 sc1\n\ts_waitcnt vmcnt(0)"
                       : "=v"(v) : "v"(myp) : "memory");
          v0 = (u64)v.x | ((u64)v.y << 32);
          v1 = (u64)v.z | ((u64)v.w << 32);
        }
        if (((v0 & M) == want) && ((v1 & M) == want)) break;
        ++it;
      }
      const int row = tid >> 8;          // 0/1
      const int e   = tid & 255;         // 16B pair index within the row
      u64* dst = (u64*)&As[row * RS + (e << 3)];   // e*16 bytes, 16B-aligned
      dst[0] = v0; dst[1] = v1;
    }
    __syncthreads();

    // ---- MFMA: M=2, K=1088 per wave, 34 x 16x16x32, 2 interleaved acc chains.
    // Unconditional A read, row = m16&1: 8 lanes/address -> free LDS broadcast;
    // lanes m16>=2 feed garbage into D rows 2..15 which are never read.
    f32x4 acc0 = {0.f,0.f,0.f,0.f}, acc1 = {0.f,0.f,0.f,0.f};
    {
      const unsigned short* Ab = &As[(m16 & 1) * RS + ks * 1088 + (q << 3)];
      #pragma unroll
      for (int f = 0; f < 34; f += 2){
        short8 a0 = *((const short8*)(Ab + (f << 5)));
        short8 a1 = *((const short8*)(Ab + ((f + 1) << 5)));
        acc0 = __builtin_amdgcn_mfma_f32_16x16x32_bf16(a0, Bf[f],     acc0, 0, 0, 0);
        acc1 = __builtin_amdgcn_mfma_f32_16x16x32_bf16(a1, Bf[f + 1], acc1, 0, 0, 0);
      }
    }
    // C/D: col=l&15, row=q*4+reg -> batch rows 0,1 live in lanes 0..15, regs 0,1
    float p0 = acc0[0] + acc1[0];
    float p1 = acc0[1] + acc1[1];
    if (ks == 1 && l < 16){
      red[t & 1][cg][m16][0] = p0;
      red[t & 1][cg][m16][1] = p1;
    }
    __syncthreads();

    // ---- ks==0 lanes<16: reduce, tanh, leak, publish FIRST, then out stores ----
    if (ks == 0 && l < 16){
      p0 += red[t & 1][cg][m16][0];
      p1 += red[t & 1][cg][m16][1];
      float nv0 = 0.5f * s0 + 0.5f * tanh_fast(p0 + bias);
      float nv1 = 0.5f * s1 + 0.5f * tanh_fast(p1 + bias);
      s0 = nv0; s1 = nv1;
      const u32 bit = (u32)(((t + 1) >> 1) & 1);
      u32 b0 = ((u32)f2bf(nv0) & 0xFFFEu) | bit;   // tag-bit in bf16 LSB
      u32 b1 = ((u32)f2bf(nv1) & 0xFFFEu) | bit;
      // pack 4 lanes' cols into one u64 (valid on lanes m16%4==0)
      u32 pr0 = b0 | (((u32)__shfl_xor((int)b0, 1)) << 16);
      u32 pr1 = b1 | (((u32)__shfl_xor((int)b1, 1)) << 16);
      u64 e0 = (u64)pr0 | ((u64)(u32)__shfl_xor((int)pr0, 2) << 32);
      u64 e1 = (u64)pr1 | ((u64)(u32)__shfl_xor((int)pr1, 2) << 32);
      const int u = colw0 + m16;
      if ((m16 & 3) == 0){
        u64* exw = ex + ((size_t)((t + 1) & 1) * 8 + r0) * 512;
        const int p = (colw0 + m16) >> 2;
        // publish via RMW: executes at the coherence point and leaves the line
        // LLC-resident so consumer polls hit the MALL instead of DRAM.
        (void)__hip_atomic_exchange(&exw[p],       e0, AG);
        (void)__hip_atomic_exchange(&exw[512 + p], e1, AG);
      }
      float pw0 = (u & 1) ? nv0 : nv0 * nv0;       // PowerIndex: even u squared
      float pw1 = (u & 1) ? nv1 : nv1 * nv1;
      out[((size_t)r0 * 1024 + t) * 2176 + 128 + u] = pw0;
      out[((size_t)(r0 + 1) * 1024 + t) * 2176 + 128 + u] = pw1;
    }
    // no third barrier: As reads complete before barrier 2; red is parity-double-buffered
  }
}

extern "C" void kernel_launch(void* const* d_in, const int* in_sizes, int n_in,
                              void* d_out, int out_size, void* d_ws, size_t ws_size,
                              hipStream_t stream){
  const float* inputs = (const float*)d_in[0];   // [8,1024,128]
  const float* w_in   = (const float*)d_in[1];   // [128,2048]
  const float* b_in   = (const float*)d_in[2];   // [2048]
  const float* w_res  = (const float*)d_in[3];   // [2048,2048]
  float* out = (float*)d_out;

  u64* ex = (u64*)d_ws;                                         // 2*8*512*8 = 65536 B
  unsigned short* Bsw = (unsigned short*)((char*)d_ws + 65536); // 8,912,896 B swizzled weights

  exinit_kernel<<<32, 256, 0, stream>>>(ex);
  bswz_kernel<<<2176, 256, 0, stream>>>(w_res, w_in, Bsw);
  copy_in_kernel<<<1024, 256, 0, stream>>>(inputs, out);
  esn_persist<<<128, 512, 0, stream>>>(inputs, b_in, Bsw, ex, out);
}